// Round 1
// baseline (739.141 us; speedup 1.0000x reference)
//
#include <hip/hip_runtime.h>

// Butterfly multiply, B=16384, N=2048, LOG_N=11, nstacks=nblocks=1, increasing stride.
// out[e] at stage st (s=2^st): pair (lo, hi=lo+s), p = (e>>(st+1))<<st | (e & (s-1))
//   new_lo = t[st,p,0,0]*lo + t[st,p,0,1]*hi
//   new_hi = t[st,p,1,0]*lo + t[st,p,1,1]*hi
// twiddle flat offset: st*4096 + p*4 + i*2 + j  (floats)

constexpr int BATCH = 16384;
constexpr int N = 2048;
constexpr int REGS = 32;            // elements per lane per row (N / 64)
constexpr int ROWS = 4;             // rows per wave (twiddle reuse factor)
constexpr int WAVES_PER_BLOCK = 4;
constexpr int BLOCK = 64 * WAVES_PER_BLOCK;

__global__ __launch_bounds__(BLOCK, 2)
void butterfly_kernel(const float* __restrict__ x,
                      const float* __restrict__ tw,
                      const float* __restrict__ bias,
                      float* __restrict__ out)
{
    const int lane = threadIdx.x & 63;
    const int wid  = blockIdx.x * WAVES_PER_BLOCK + (threadIdx.x >> 6);
    const size_t row0 = (size_t)wid * ROWS;

    float v[ROWS][REGS];

    // ---- load ROWS rows, float4-vectorized; layout e = lane*32 + r
    #pragma unroll
    for (int rr = 0; rr < ROWS; ++rr) {
        const float4* src = (const float4*)(x + (row0 + rr) * N + lane * REGS);
        #pragma unroll
        for (int t = 0; t < REGS / 4; ++t) {
            float4 f = src[t];
            v[rr][4*t+0] = f.x; v[rr][4*t+1] = f.y;
            v[rr][4*t+2] = f.z; v[rr][4*t+3] = f.w;
        }
    }

    // ---- stages 0..4 (s = 1..16): both pair halves within the lane
    #pragma unroll
    for (int st = 0; st < 5; ++st) {
        const int s = 1 << st;
        const float* twst = tw + (st << 12);    // st * 1024 * 4 floats
        #pragma unroll
        for (int r = 0; r < REGS; ++r) {
            if (r & s) continue;                 // visit each pair once (at lo)
            const int e = lane * REGS + r;
            const int p = ((e >> (st + 1)) << st) | (e & (s - 1));
            const float4 t4 = *(const float4*)(twst + 4 * p);
            #pragma unroll
            for (int rr = 0; rr < ROWS; ++rr) {
                const float lo = v[rr][r];
                const float hi = v[rr][r + s];
                v[rr][r]     = fmaf(t4.x, lo, t4.y * hi);
                v[rr][r + s] = fmaf(t4.z, lo, t4.w * hi);
            }
        }
    }

    // ---- stages 5..10 (s = 32..1024): partner in lane ^ m, same register
    #pragma unroll
    for (int st = 5; st < 11; ++st) {
        const int m = 1 << (st - 5);
        const int hiHalf = (lane >> (st - 5)) & 1;   // which row of the 2x2 I need
        const float* twst = tw + (st << 12);
        #pragma unroll
        for (int r = 0; r < REGS; ++r) {
            const int e = lane * REGS + r;
            const int p = ((e >> (st + 1)) << st) | (e & ((1 << st) - 1));
            const float2 t2 = *(const float2*)(twst + 4 * p + 2 * hiHalf);
            #pragma unroll
            for (int rr = 0; rr < ROWS; ++rr) {
                const float mine = v[rr][r];
                const float part = __shfl_xor(mine, m, 64);
                const float lo = hiHalf ? part : mine;
                const float hi = hiHalf ? mine : part;
                v[rr][r] = fmaf(t2.x, lo, t2.y * hi);
            }
        }
    }

    // ---- store with bias (bias chunk reused across the 4 rows)
    #pragma unroll
    for (int t = 0; t < REGS / 4; ++t) {
        const float4 b = *(const float4*)(bias + lane * REGS + 4 * t);
        #pragma unroll
        for (int rr = 0; rr < ROWS; ++rr) {
            float4 o;
            o.x = v[rr][4*t+0] + b.x;
            o.y = v[rr][4*t+1] + b.y;
            o.z = v[rr][4*t+2] + b.z;
            o.w = v[rr][4*t+3] + b.w;
            *(float4*)(out + (row0 + rr) * N + lane * REGS + 4 * t) = o;
        }
    }
}

extern "C" void kernel_launch(void* const* d_in, const int* in_sizes, int n_in,
                              void* d_out, int out_size, void* d_ws, size_t ws_size,
                              hipStream_t stream) {
    const float* x    = (const float*)d_in[0];
    const float* tw   = (const float*)d_in[1];
    const float* bias = (const float*)d_in[2];
    float* out = (float*)d_out;

    const int total_waves = BATCH / ROWS;            // 4096 waves
    const int grid = total_waves / WAVES_PER_BLOCK;  // 1024 blocks
    butterfly_kernel<<<grid, BLOCK, 0, stream>>>(x, tw, bias, out);
}